// Round 3
// 1556.569 us; speedup vs baseline: 1.0907x; 1.0907x over previous
//
#include <hip/hip_runtime.h>

#define BB 256
#define TT 1024
#define II 128
#define GG 512   // 2C
#define CC 256
#define L2E 1.44269504f

typedef _Float16 f16;
typedef _Float16 h8_t __attribute__((ext_vector_type(8)));
typedef float f4_t __attribute__((ext_vector_type(4)));
typedef unsigned short ushort_t;
typedef unsigned short us4_t __attribute__((ext_vector_type(4)));

static __device__ __forceinline__ float fast_rcp(float x) {
#if __has_builtin(__builtin_amdgcn_rcpf)
    return __builtin_amdgcn_rcpf(x);
#else
    return 1.f / x;
#endif
}
static __device__ __forceinline__ float fast_exp2(float x) {
#if __has_builtin(__builtin_amdgcn_exp2f)
    return __builtin_amdgcn_exp2f(x);
#else
    return exp2f(x);
#endif
}

// ---- kernel 1: Kt[n][k] = f16(kernel[k][n])  (128x512 -> 512x128) ----
__global__ void kt_transpose(const float* __restrict__ kin, f16* __restrict__ kt) {
    int idx = blockIdx.x * 256 + threadIdx.x;   // 65536 total
    int k = idx >> 9;
    int n = idx & 511;
    kt[n * II + k] = (f16)kin[k * GG + n];
}

// ---- kernel 2: blocked xz layout ----
// xz3[((t*16 + g)*512 + col)*16 + bl]  where batch b = g*16 + bl.
// Each janet WG-step (t, g) then reads ONE contiguous 16 KB block.
// Value stored: f16( (x@K + bias) * s_col ), s = L2E (f-half) / 2*L2E (g-half).
__global__ __launch_bounds__(256)
void gemm_xz(const float* __restrict__ x, const f16* __restrict__ kt,
             const float* __restrict__ bias, ushort_t* __restrict__ xz) {
    const int  ntile = blockIdx.x;   // 0..3   (128 cols)
    const long mtile = blockIdx.y;   // 0..2047 (128 rows of m' = t*256+b)
    const int wave = threadIdx.x >> 6;
    const int lane = threadIdx.x & 63;
    const int wm = (wave & 1) * 64;
    const int wn = (wave >> 1) * 64;
    const int lm = lane & 15;
    const int q  = lane >> 4;

    f4_t acc[4][4];
#pragma unroll
    for (int mi = 0; mi < 4; ++mi)
#pragma unroll
        for (int ni = 0; ni < 4; ++ni)
            acc[mi][ni] = (f4_t){0.f, 0.f, 0.f, 0.f};

#pragma unroll
    for (int kc = 0; kc < 4; ++kc) {
        h8_t a[4], bf[4];
#pragma unroll
        for (int mi = 0; mi < 4; ++mi) {
            const int rowm = (int)(mtile * 128) + wm + mi * 16 + lm;   // m'
            const int b  = rowm & 255;
            const int tt = rowm >> 8;
            const float* ap = x + (size_t)b * (TT * II) + (size_t)tt * II + kc * 32 + q * 8;
            f4_t p0 = *(const f4_t*)ap;
            f4_t p1 = *(const f4_t*)(ap + 4);
            h8_t tv;
            tv[0] = (f16)p0[0]; tv[1] = (f16)p0[1]; tv[2] = (f16)p0[2]; tv[3] = (f16)p0[3];
            tv[4] = (f16)p1[0]; tv[5] = (f16)p1[1]; tv[6] = (f16)p1[2]; tv[7] = (f16)p1[3];
            a[mi] = tv;
        }
#pragma unroll
        for (int ni = 0; ni < 4; ++ni) {
            const f16* bp = kt + (size_t)(ntile * 128 + wn + ni * 16 + lm) * II + kc * 32 + q * 8;
            bf[ni] = *(const h8_t*)bp;
        }
#pragma unroll
        for (int mi = 0; mi < 4; ++mi)
#pragma unroll
            for (int ni = 0; ni < 4; ++ni)
                acc[mi][ni] = __builtin_amdgcn_mfma_f32_16x16x32_f16(a[mi], bf[ni], acc[mi][ni], 0, 0, 0);
    }

    // epilogue: C/D layout col=lane&15, row=(lane>>4)*4+reg (m89).
    // 4 regs (r=0..3) are 4 consecutive batches -> one dwordx2 store each,
    // and a wave-instruction covers a contiguous 512 B burst.
#pragma unroll
    for (int mi = 0; mi < 4; ++mi) {
        const int rowm0 = (int)(mtile * 128) + wm + mi * 16 + q * 4;
        const int t  = rowm0 >> 8;
        const int b0 = rowm0 & 255;
        const int gq = b0 >> 4;          // bl0 = q*4 (16-aligned tile base)
#pragma unroll
        for (int ni = 0; ni < 4; ++ni) {
            const int col = ntile * 128 + wn + ni * 16 + lm;
            const float bv = bias[col];
            const float s  = (col < CC) ? L2E : (2.0f * L2E);
            us4_t v;
#pragma unroll
            for (int r = 0; r < 4; ++r) {
                f16 hv = (f16)((acc[mi][ni][r] + bv) * s);
                v[r] = *(ushort_t*)&hv;
            }
            *(us4_t*)(xz + (((size_t)t * 16 + gq) * 512 + col) * 16 + q * 4) = v;
        }
    }
}

// ---- kernel 3: MFMA recurrence. 16 WGs x 512 thr, 16 batches per WG. ----
// Wave w owns n-tiles {w, w+8, w+16, w+24}; pair p = (ni=p f-tile, ni=p+2 g-tile).
// Pair-major MFMA groups (pair0's 16 MFMAs, then pair1's), so pair0's sigmoid/tanh
// + h-write overlap pair1's MFMA drain instead of serializing after the whole MFMA
// phase. xz loads are 4x dwordx2 from the blocked layout (one contiguous 16 KB block
// per WG-step). In-loop barrier waits lgkmcnt only so global prefetch stays in
// flight across steps.
#define STEP(T, PF, PP, HRD, HWR) do {                                               \
    h8_t af[8];                                                                      \
    _Pragma("unroll") for (int kt = 0; kt < 8; ++kt)                                 \
        af[kt] = *(const h8_t*)((HRD) + lm * 264 + kt * 32 + q * 8);                 \
    f4_t acc[4];                                                                     \
    _Pragma("unroll") for (int ni = 0; ni < 4; ++ni) {                               \
        f4_t av;                                                                     \
        _Pragma("unroll") for (int r = 0; r < 4; ++r) {                              \
            ushort_t u = (PF)[ni * 4 + r];                                           \
            f16 hv = *(f16*)&u;                                                      \
            av[r] = (float)hv;                                                       \
        }                                                                            \
        acc[ni] = av;                                                                \
    }                                                                                \
    if ((T) + 2 < TT) {                                                              \
        _Pragma("unroll") for (int ni = 0; ni < 4; ++ni) {                           \
            us4_t v = *(const us4_t*)((PP) + ni * 2048);                             \
            (PF)[ni * 4 + 0] = v[0];                                                 \
            (PF)[ni * 4 + 1] = v[1];                                                 \
            (PF)[ni * 4 + 2] = v[2];                                                 \
            (PF)[ni * 4 + 3] = v[3];                                                 \
        }                                                                            \
        (PP) += 2 * 131072;                                                          \
    }                                                                                \
    /* pair 0 MFMA group (finishes ~half-phase early) */                             \
    _Pragma("unroll") for (int kt = 0; kt < 8; ++kt) {                               \
        acc[0] = __builtin_amdgcn_mfma_f32_16x16x32_f16(af[kt], bw[0][kt], acc[0], 0, 0, 0); \
        acc[2] = __builtin_amdgcn_mfma_f32_16x16x32_f16(af[kt], bw[2][kt], acc[2], 0, 0, 0); \
    }                                                                                \
    /* pair 1 MFMA group */                                                          \
    _Pragma("unroll") for (int kt = 0; kt < 8; ++kt) {                               \
        acc[1] = __builtin_amdgcn_mfma_f32_16x16x32_f16(af[kt], bw[1][kt], acc[1], 0, 0, 0); \
        acc[3] = __builtin_amdgcn_mfma_f32_16x16x32_f16(af[kt], bw[3][kt], acc[3], 0, 0, 0); \
    }                                                                                \
    /* pair 0 sigmoid/tanh + write (overlaps pair 1 MFMA drain) */                   \
    _Pragma("unroll") for (int r = 0; r < 4; ++r) {                                  \
        float zf = acc[0][r];                                                        \
        float zg = acc[2][r];                                                        \
        float ef = fast_exp2(-zf);                                                   \
        float eg = fast_exp2(-fabsf(zg));                                            \
        float t1 = (zg < 0.f) ? -ef : ef;                                            \
        float cv = cst[0][r];                                                        \
        float num = fmaf(cv, eg, cv) + fmaf(-t1, eg, t1);                            \
        float den = (1.f + ef) * (1.f + eg);                                         \
        cst[0][r] = num * fast_rcp(den);                                             \
        (HWR)[(q * 4 + r) * 264 + wave * 16 + lm] = (f16)cst[0][r];                  \
    }                                                                                \
    /* pair 1 sigmoid/tanh + write */                                                \
    _Pragma("unroll") for (int r = 0; r < 4; ++r) {                                  \
        float zf = acc[1][r];                                                        \
        float zg = acc[3][r];                                                        \
        float ef = fast_exp2(-zf);                                                   \
        float eg = fast_exp2(-fabsf(zg));                                            \
        float t1 = (zg < 0.f) ? -ef : ef;                                            \
        float cv = cst[1][r];                                                        \
        float num = fmaf(cv, eg, cv) + fmaf(-t1, eg, t1);                            \
        float den = (1.f + ef) * (1.f + eg);                                         \
        cst[1][r] = num * fast_rcp(den);                                             \
        (HWR)[(q * 4 + r) * 264 + (wave + 8) * 16 + lm] = (f16)cst[1][r];            \
    }                                                                                \
    asm volatile("s_waitcnt lgkmcnt(0)\n\ts_barrier" ::: "memory");                  \
} while (0)

__global__ __launch_bounds__(512, 2)
void janet_rec(const float* __restrict__ rk, const float* __restrict__ dw,
               const float* __restrict__ db, const ushort_t* __restrict__ xz,
               float* __restrict__ out) {
    const int g = blockIdx.x;            // batch group: batches g*16 .. g*16+15
    const int tid = threadIdx.x;
    const int wave = tid >> 6;
    const int lane = tid & 63;
    const int lm = lane & 15;
    const int q  = lane >> 4;

    // resident pre-scaled recurrent weights: bw[ni][kt][j] = s * R[kt*32+q*8+j][(wave+8*ni)*16+lm]
    h8_t bw[4][8];
#pragma unroll
    for (int ni = 0; ni < 4; ++ni) {
        const float s = (ni < 2) ? L2E : (2.0f * L2E);
#pragma unroll
        for (int kt = 0; kt < 8; ++kt) {
            h8_t tv;
#pragma unroll
            for (int j = 0; j < 8; ++j)
                tv[j] = (f16)(s * rk[(size_t)(kt * 32 + q * 8 + j) * GG + (wave + 8 * ni) * 16 + lm]);
            bw[ni][kt] = tv;
        }
    }

    __shared__ __align__(16) f16 hb[2][16][264];
    f16* h0 = &hb[0][0][0];
    f16* h1 = &hb[1][0][0];
    for (int i = tid; i < 2 * 16 * 264; i += 512) ((f16*)hb)[i] = (f16)0.f;

    float cst[2][4];
#pragma unroll
    for (int ni = 0; ni < 2; ++ni)
#pragma unroll
        for (int r = 0; r < 4; ++r) cst[ni][r] = 0.f;

    // per-thread xz base (blocked layout): value(t, b=g*16+q*4+r, col=wave*16+lm+ni*128)
    // at PB[t*131072 + ni*2048 + r]; the 4 r-values are contiguous -> dwordx2 loads.
    const ushort_t* PB = xz + (size_t)g * 8192 + (wave * 16 + lm) * 16 + q * 4;
    const ushort_t* p0 = PB + 2 * 131072;       // refill source for pf0 (t=2,4,...)
    const ushort_t* p1 = PB + 3 * 131072;       // refill source for pf1 (t=3,5,...)

    ushort_t pf0[16], pf1[16];
#pragma unroll
    for (int ni = 0; ni < 4; ++ni) {
        us4_t v0 = *(const us4_t*)(PB + ni * 2048);
        us4_t v1 = *(const us4_t*)(PB + 131072 + ni * 2048);
        pf0[ni * 4 + 0] = v0[0]; pf0[ni * 4 + 1] = v0[1];
        pf0[ni * 4 + 2] = v0[2]; pf0[ni * 4 + 3] = v0[3];
        pf1[ni * 4 + 0] = v1[0]; pf1[ni * 4 + 1] = v1[1];
        pf1[ni * 4 + 2] = v1[2]; pf1[ni * 4 + 3] = v1[3];
    }
    __syncthreads();

#pragma unroll 1
    for (int t = 0; t < TT; t += 2) {
        STEP(t,     pf0, p0, h0, h1);
        STEP(t + 1, pf1, p1, h1, h0);
    }

    // final dense: out[b] = h_final @ dense_w + db
    __shared__ float hf[16][256];
#pragma unroll
    for (int ni = 0; ni < 2; ++ni)
#pragma unroll
        for (int r = 0; r < 4; ++r)
            hf[q * 4 + r][(wave + 8 * ni) * 16 + lm] = cst[ni][r];
    __syncthreads();
    if (tid < 160) {
        const int bi = tid / 10, o = tid % 10;
        float acc = db[o];
#pragma unroll 8
        for (int cc = 0; cc < CC; ++cc) acc = fmaf(hf[bi][cc], dw[cc * 10 + o], acc);
        out[(g * 16 + bi) * 10 + o] = acc;
    }
}

// ---- guard ----
__global__ void ws_too_small(float* out, float wssz) {
    int i = blockIdx.x * 256 + threadIdx.x;
    if (i < BB * 10) out[i] = (i == 0) ? wssz : 0.f;
}

extern "C" void kernel_launch(void* const* d_in, const int* in_sizes, int n_in,
                              void* d_out, int out_size, void* d_ws, size_t ws_size,
                              hipStream_t stream) {
    const float* x   = (const float*)d_in[0];
    const float* kin = (const float*)d_in[1];
    const float* rk  = (const float*)d_in[2];
    const float* rb  = (const float*)d_in[3];
    const float* dw  = (const float*)d_in[4];
    const float* db  = (const float*)d_in[5];
    float* out = (float*)d_out;

    const size_t xz_bytes = (size_t)BB * TT * GG * 2;   // 268,435,456
    const size_t kt_bytes = (size_t)GG * II * 2;        // 131,072
    if (ws_size < xz_bytes + kt_bytes) {
        ws_too_small<<<10, 256, 0, stream>>>(out, (float)ws_size);
        return;
    }

    ushort_t* xz = (ushort_t*)d_ws;
    f16* kt = (f16*)((char*)d_ws + xz_bytes);

    kt_transpose<<<256, 256, 0, stream>>>(kin, kt);
    gemm_xz<<<dim3(4, 2048), 256, 0, stream>>>(x, kt, rb, xz);
    janet_rec<<<16, 512, 0, stream>>>(rk, dw, db, xz, out);
}

// Round 4
// 1464.157 us; speedup vs baseline: 1.1595x; 1.0631x over previous
//
#include <hip/hip_runtime.h>

#define BB 256
#define TT 1024
#define II 128
#define GG 512   // 2C
#define CC 256
#define L2E 1.44269504f

typedef _Float16 f16;
typedef _Float16 h8_t __attribute__((ext_vector_type(8)));
typedef float f4_t __attribute__((ext_vector_type(4)));
typedef unsigned short ushort_t;
typedef unsigned short us4_t __attribute__((ext_vector_type(4)));

static __device__ __forceinline__ float fast_rcp(float x) {
#if __has_builtin(__builtin_amdgcn_rcpf)
    return __builtin_amdgcn_rcpf(x);
#else
    return 1.f / x;
#endif
}
static __device__ __forceinline__ float fast_exp2(float x) {
#if __has_builtin(__builtin_amdgcn_exp2f)
    return __builtin_amdgcn_exp2f(x);
#else
    return exp2f(x);
#endif
}

// ---- kernel 1: Kt[n][k] = f16(kernel[k][n])  (128x512 -> 512x128) ----
__global__ void kt_transpose(const float* __restrict__ kin, f16* __restrict__ kt) {
    int idx = blockIdx.x * 256 + threadIdx.x;   // 65536 total
    int k = idx >> 9;
    int n = idx & 511;
    kt[n * II + k] = (f16)kin[k * GG + n];
}

// ---- kernel 2: blocked xz layout, merged-ntile blocks ----
// xz[((t*16 + g)*512 + col)*16 + bl], batch b = g*16 + bl.
// One WG = 128 m'-rows x ALL 512 cols (8 waves, 2x4 wave grid). A-rows are read
// and converted ONCE chip-wide (old version: 4x redundant via the ntile grid dim),
// and 512-thread blocks give 2 waves/SIMD for load-latency hiding.
__global__ __launch_bounds__(512, 2)
void gemm_xz(const float* __restrict__ x, const f16* __restrict__ kt,
             const float* __restrict__ bias, ushort_t* __restrict__ xz) {
    const long mtile = blockIdx.x;   // 0..2047 (128 rows of m' = t*256+b)
    const int wave = threadIdx.x >> 6;
    const int lane = threadIdx.x & 63;
    const int wm = (wave & 1) * 64;
    const int wn = (wave >> 1) * 128;   // 0,128,256,384
    const int lm = lane & 15;
    const int q  = lane >> 4;

    f4_t acc[4][8];
#pragma unroll
    for (int mi = 0; mi < 4; ++mi)
#pragma unroll
        for (int nj = 0; nj < 8; ++nj)
            acc[mi][nj] = (f4_t){0.f, 0.f, 0.f, 0.f};

#pragma unroll
    for (int kc = 0; kc < 4; ++kc) {
        h8_t a[4], bf[8];
#pragma unroll
        for (int mi = 0; mi < 4; ++mi) {
            const int rowm = (int)(mtile * 128) + wm + mi * 16 + lm;   // m'
            const int b  = rowm & 255;
            const int tt = rowm >> 8;
            const float* ap = x + (size_t)b * (TT * II) + (size_t)tt * II + kc * 32 + q * 8;
            f4_t p0 = *(const f4_t*)ap;
            f4_t p1 = *(const f4_t*)(ap + 4);
            h8_t tv;
            tv[0] = (f16)p0[0]; tv[1] = (f16)p0[1]; tv[2] = (f16)p0[2]; tv[3] = (f16)p0[3];
            tv[4] = (f16)p1[0]; tv[5] = (f16)p1[1]; tv[6] = (f16)p1[2]; tv[7] = (f16)p1[3];
            a[mi] = tv;
        }
#pragma unroll
        for (int nj = 0; nj < 8; ++nj) {
            const f16* bp = kt + (size_t)(wn + nj * 16 + lm) * II + kc * 32 + q * 8;
            bf[nj] = *(const h8_t*)bp;
        }
#pragma unroll
        for (int mi = 0; mi < 4; ++mi)
#pragma unroll
            for (int nj = 0; nj < 8; ++nj)
                acc[mi][nj] = __builtin_amdgcn_mfma_f32_16x16x32_f16(a[mi], bf[nj], acc[mi][nj], 0, 0, 0);
    }

    // epilogue: C/D layout col=lane&15, row=(lane>>4)*4+reg (m89).
    // us4 store = 4 consecutive batches; each wave-instruction is a coalesced
    // 512 B burst in the blocked layout.
#pragma unroll
    for (int mi = 0; mi < 4; ++mi) {
        const int rowm0 = (int)(mtile * 128) + wm + mi * 16 + q * 4;
        const int t  = rowm0 >> 8;
        const int b0 = rowm0 & 255;
        const int gq = b0 >> 4;          // bl0 = q*4 (16-aligned tile base)
#pragma unroll
        for (int nj = 0; nj < 8; ++nj) {
            const int col = wn + nj * 16 + lm;
            const float bv = bias[col];
            const float s  = (col < CC) ? L2E : (2.0f * L2E);
            us4_t v;
#pragma unroll
            for (int r = 0; r < 4; ++r) {
                f16 hv = (f16)((acc[mi][nj][r] + bv) * s);
                v[r] = *(ushort_t*)&hv;
            }
            *(us4_t*)(xz + (((size_t)t * 16 + gq) * 512 + col) * 16 + q * 4) = v;
        }
    }
}

// ---- kernel 3: MFMA recurrence, split-barrier pipeline. 16 WGs x 512 thr. ----
// Wave w owns n-tiles {w, w+8, w+16, w+24}; pair p = (ni=p f-tile, ni=p+2 g-tile).
// h cells 0..127 (low) are produced by pair0, cells 128..255 (high) by pair1.
// Next step's kt0..3 MFMAs need only h_low -> step pipeline:
//   [MFMA kt0..3 all accs]  (h_low(T) guaranteed by BAR_b of step T-1)
//   BAR_a  (h_high(T) visible)
//   [read af_high; MFMA kt4..7: acc0/2 then acc1/3]
//   valu0 + write h_low(T+1)
//   BAR_b  (h_low(T+1) visible)
//   valu1 + write h_high(T+1)   -> falls into next step's low MFMAs, no barrier
// The pair-1 VALU/trans tail hides under other waves' next-step MFMAs.
// Per-acc kt order stays 0..7 ascending -> bit-identical numerics.
// Safety: h double-buffered; low/high write sets are address-disjoint; every
// same-buffer cross-wave read/write pair is separated by >=1 barrier.
#define STEP(T, PF, PP, HRD, HWR) do {                                               \
    h8_t af[8];                                                                      \
    _Pragma("unroll") for (int kt = 0; kt < 4; ++kt)                                 \
        af[kt] = *(const h8_t*)((HRD) + lm * 264 + kt * 32 + q * 8);                 \
    f4_t acc[4];                                                                     \
    _Pragma("unroll") for (int ni = 0; ni < 4; ++ni) {                               \
        f4_t av;                                                                     \
        _Pragma("unroll") for (int r = 0; r < 4; ++r) {                              \
            ushort_t u = (PF)[ni * 4 + r];                                           \
            f16 hv = *(f16*)&u;                                                      \
            av[r] = (float)hv;                                                       \
        }                                                                            \
        acc[ni] = av;                                                                \
    }                                                                                \
    if ((T) + 2 < TT) {                                                              \
        _Pragma("unroll") for (int ni = 0; ni < 4; ++ni) {                           \
            us4_t v = *(const us4_t*)((PP) + ni * 2048);                             \
            (PF)[ni * 4 + 0] = v[0];                                                 \
            (PF)[ni * 4 + 1] = v[1];                                                 \
            (PF)[ni * 4 + 2] = v[2];                                                 \
            (PF)[ni * 4 + 3] = v[3];                                                 \
        }                                                                            \
        (PP) += 2 * 131072;                                                          \
    }                                                                                \
    /* low half: kt 0..3, pair-major */                                              \
    _Pragma("unroll") for (int kt = 0; kt < 4; ++kt) {                               \
        acc[0] = __builtin_amdgcn_mfma_f32_16x16x32_f16(af[kt], bw[0][kt], acc[0], 0, 0, 0); \
        acc[2] = __builtin_amdgcn_mfma_f32_16x16x32_f16(af[kt], bw[2][kt], acc[2], 0, 0, 0); \
    }                                                                                \
    _Pragma("unroll") for (int kt = 0; kt < 4; ++kt) {                               \
        acc[1] = __builtin_amdgcn_mfma_f32_16x16x32_f16(af[kt], bw[1][kt], acc[1], 0, 0, 0); \
        acc[3] = __builtin_amdgcn_mfma_f32_16x16x32_f16(af[kt], bw[3][kt], acc[3], 0, 0, 0); \
    }                                                                                \
    asm volatile("s_waitcnt lgkmcnt(0)\n\ts_barrier" ::: "memory");  /* BAR_a */     \
    _Pragma("unroll") for (int kt = 4; kt < 8; ++kt)                                 \
        af[kt] = *(const h8_t*)((HRD) + lm * 264 + kt * 32 + q * 8);                 \
    /* high half: kt 4..7, pair-major (acc0/2 first so valu0 can start early) */     \
    _Pragma("unroll") for (int kt = 4; kt < 8; ++kt) {                               \
        acc[0] = __builtin_amdgcn_mfma_f32_16x16x32_f16(af[kt], bw[0][kt], acc[0], 0, 0, 0); \
        acc[2] = __builtin_amdgcn_mfma_f32_16x16x32_f16(af[kt], bw[2][kt], acc[2], 0, 0, 0); \
    }                                                                                \
    _Pragma("unroll") for (int kt = 4; kt < 8; ++kt) {                               \
        acc[1] = __builtin_amdgcn_mfma_f32_16x16x32_f16(af[kt], bw[1][kt], acc[1], 0, 0, 0); \
        acc[3] = __builtin_amdgcn_mfma_f32_16x16x32_f16(af[kt], bw[3][kt], acc[3], 0, 0, 0); \
    }                                                                                \
    /* pair 0 sigmoid/tanh + write h_low(T+1) */                                     \
    _Pragma("unroll") for (int r = 0; r < 4; ++r) {                                  \
        float zf = acc[0][r];                                                        \
        float zg = acc[2][r];                                                        \
        float ef = fast_exp2(-zf);                                                   \
        float eg = fast_exp2(-fabsf(zg));                                            \
        float t1 = (zg < 0.f) ? -ef : ef;                                            \
        float cv = cst[0][r];                                                        \
        float num = fmaf(cv, eg, cv) + fmaf(-t1, eg, t1);                            \
        float den = (1.f + ef) * (1.f + eg);                                         \
        cst[0][r] = num * fast_rcp(den);                                             \
        (HWR)[(q * 4 + r) * 264 + wave * 16 + lm] = (f16)cst[0][r];                  \
    }                                                                                \
    asm volatile("s_waitcnt lgkmcnt(0)\n\ts_barrier" ::: "memory");  /* BAR_b */     \
    /* pair 1 sigmoid/tanh + write h_high(T+1); next step's low MFMAs follow */      \
    _Pragma("unroll") for (int r = 0; r < 4; ++r) {                                  \
        float zf = acc[1][r];                                                        \
        float zg = acc[3][r];                                                        \
        float ef = fast_exp2(-zf);                                                   \
        float eg = fast_exp2(-fabsf(zg));                                            \
        float t1 = (zg < 0.f) ? -ef : ef;                                            \
        float cv = cst[1][r];                                                        \
        float num = fmaf(cv, eg, cv) + fmaf(-t1, eg, t1);                            \
        float den = (1.f + ef) * (1.f + eg);                                         \
        cst[1][r] = num * fast_rcp(den);                                             \
        (HWR)[(q * 4 + r) * 264 + (wave + 8) * 16 + lm] = (f16)cst[1][r];            \
    }                                                                                \
} while (0)

__global__ __launch_bounds__(512, 2)
void janet_rec(const float* __restrict__ rk, const float* __restrict__ dw,
               const float* __restrict__ db, const ushort_t* __restrict__ xz,
               float* __restrict__ out) {
    const int g = blockIdx.x;            // batch group: batches g*16 .. g*16+15
    const int tid = threadIdx.x;
    const int wave = tid >> 6;
    const int lane = tid & 63;
    const int lm = lane & 15;
    const int q  = lane >> 4;

    // resident pre-scaled recurrent weights: bw[ni][kt][j] = s * R[kt*32+q*8+j][(wave+8*ni)*16+lm]
    h8_t bw[4][8];
#pragma unroll
    for (int ni = 0; ni < 4; ++ni) {
        const float s = (ni < 2) ? L2E : (2.0f * L2E);
#pragma unroll
        for (int kt = 0; kt < 8; ++kt) {
            h8_t tv;
#pragma unroll
            for (int j = 0; j < 8; ++j)
                tv[j] = (f16)(s * rk[(size_t)(kt * 32 + q * 8 + j) * GG + (wave + 8 * ni) * 16 + lm]);
            bw[ni][kt] = tv;
        }
    }

    __shared__ __align__(16) f16 hb[2][16][264];
    f16* h0 = &hb[0][0][0];
    f16* h1 = &hb[1][0][0];
    for (int i = tid; i < 2 * 16 * 264; i += 512) ((f16*)hb)[i] = (f16)0.f;

    float cst[2][4];
#pragma unroll
    for (int ni = 0; ni < 2; ++ni)
#pragma unroll
        for (int r = 0; r < 4; ++r) cst[ni][r] = 0.f;

    // per-thread xz base (blocked layout): value(t, b=g*16+q*4+r, col=wave*16+lm+ni*128)
    // at PB[t*131072 + ni*2048 + r]; the 4 r-values are contiguous -> dwordx2 loads.
    const ushort_t* PB = xz + (size_t)g * 8192 + (wave * 16 + lm) * 16 + q * 4;
    const ushort_t* p0 = PB + 2 * 131072;       // refill source for pf0 (t=2,4,...)
    const ushort_t* p1 = PB + 3 * 131072;       // refill source for pf1 (t=3,5,...)

    ushort_t pf0[16], pf1[16];
#pragma unroll
    for (int ni = 0; ni < 4; ++ni) {
        us4_t v0 = *(const us4_t*)(PB + ni * 2048);
        us4_t v1 = *(const us4_t*)(PB + 131072 + ni * 2048);
        pf0[ni * 4 + 0] = v0[0]; pf0[ni * 4 + 1] = v0[1];
        pf0[ni * 4 + 2] = v0[2]; pf0[ni * 4 + 3] = v0[3];
        pf1[ni * 4 + 0] = v1[0]; pf1[ni * 4 + 1] = v1[1];
        pf1[ni * 4 + 2] = v1[2]; pf1[ni * 4 + 3] = v1[3];
    }
    __syncthreads();

#pragma unroll 1
    for (int t = 0; t < TT; t += 2) {
        STEP(t,     pf0, p0, h0, h1);
        STEP(t + 1, pf1, p1, h1, h0);
    }

    // final dense: out[b] = h_final @ dense_w + db
    __shared__ float hf[16][256];
#pragma unroll
    for (int ni = 0; ni < 2; ++ni)
#pragma unroll
        for (int r = 0; r < 4; ++r)
            hf[q * 4 + r][(wave + 8 * ni) * 16 + lm] = cst[ni][r];
    __syncthreads();
    if (tid < 160) {
        const int bi = tid / 10, o = tid % 10;
        float acc = db[o];
#pragma unroll 8
        for (int cc = 0; cc < CC; ++cc) acc = fmaf(hf[bi][cc], dw[cc * 10 + o], acc);
        out[(g * 16 + bi) * 10 + o] = acc;
    }
}

// ---- guard ----
__global__ void ws_too_small(float* out, float wssz) {
    int i = blockIdx.x * 256 + threadIdx.x;
    if (i < BB * 10) out[i] = (i == 0) ? wssz : 0.f;
}

extern "C" void kernel_launch(void* const* d_in, const int* in_sizes, int n_in,
                              void* d_out, int out_size, void* d_ws, size_t ws_size,
                              hipStream_t stream) {
    const float* x   = (const float*)d_in[0];
    const float* kin = (const float*)d_in[1];
    const float* rk  = (const float*)d_in[2];
    const float* rb  = (const float*)d_in[3];
    const float* dw  = (const float*)d_in[4];
    const float* db  = (const float*)d_in[5];
    float* out = (float*)d_out;

    const size_t xz_bytes = (size_t)BB * TT * GG * 2;   // 268,435,456
    const size_t kt_bytes = (size_t)GG * II * 2;        // 131,072
    if (ws_size < xz_bytes + kt_bytes) {
        ws_too_small<<<10, 256, 0, stream>>>(out, (float)ws_size);
        return;
    }

    ushort_t* xz = (ushort_t*)d_ws;
    f16* kt = (f16*)((char*)d_ws + xz_bytes);

    kt_transpose<<<256, 256, 0, stream>>>(kin, kt);
    gemm_xz<<<2048, 512, 0, stream>>>(x, kt, rb, xz);
    janet_rec<<<16, 512, 0, stream>>>(rk, dw, db, xz, out);
}